// Round 12
// baseline (373.975 us; speedup 1.0000x reference)
//
#include <hip/hip_runtime.h>
#include <hip/hip_fp16.h>
#include <stdint.h>

#define T_ 2
#define H_ 384
#define W_ 384
#define C_ 128
#define HN_ 48
#define WN_ 48
#define NWIN_ (T_*HN_*WN_)
#define SCALE_ 0.17677669529663687f

typedef float f32x4 __attribute__((ext_vector_type(4)));
typedef _Float16 f16x8 __attribute__((ext_vector_type(8)));

// ---- workspace ----
#define WS_WFRAG 0        // 4 mats x [nt8][ks][lane][8] f16 = 131072 B
#define WS_BIASX 131072   // [he][m2][n][gr] f32 = 65536 B  (S^T-fragment layout)
#define WS_DWF   196608   // [3][64 cp][12] half2-as-uint = 9216 B
#define WS_DWB   205824   // [3][64 cp] half2-as-uint = 768 B

// ---- LDS: 32 KB, two 16KB regions, recycled ----
// t0: X_q -> X_v -> V^T[128][128B]      t1: X_k -> K -> O
#define SMEM_SZ 32768

__device__ __forceinline__ unsigned int pkh(float a, float b){
  union{__half2 h; unsigned int u;} c;
  c.h = __float22half2_rn(make_float2(a, b));
  return c.u;
}
__device__ __forceinline__ unsigned short f2h(float f){
  union{__half h; unsigned short u;} c; c.h = __float2half_rn(f); return c.u;
}
__device__ __forceinline__ __half2 u2h(unsigned int u){
  union{unsigned int u; __half2 h;} c; c.u = u; return c.h;
}
// packed-half ReLU via sign-mask (exact for non-NaN)
__device__ __forceinline__ unsigned int relu2u(__half2 v){
  union{__half2 h; unsigned int u;} c; c.h = v;
  const unsigned int m = ((c.u >> 15) & 0x00010001u) * 0xFFFFu;
  return c.u & ~m;
}
__device__ __forceinline__ int swz256(int row, int b){ return row*256 + (b ^ ((row & 15) << 4)); }
__device__ __forceinline__ int swz128(int row, int b){ return row*128 + (b ^ ((row & 7) << 4)); }

// C-frag(col=c16,row=g*4+r, 2 tiles) -> A/B-frag(row=c16,k=g*8+e)  [proven r7/r11]
__device__ __forceinline__ f16x8 xpose_frag(uint2 a, uint2 b, int l0b, int l1b, int hi){
  union{ f16x8 v; unsigned int u[4]; } r;
  const unsigned x0 = __builtin_amdgcn_ds_bpermute(l0b, (int)a.x);
  const unsigned y0 = __builtin_amdgcn_ds_bpermute(l0b, (int)b.x);
  const unsigned x1 = __builtin_amdgcn_ds_bpermute(l0b, (int)a.y);
  const unsigned y1 = __builtin_amdgcn_ds_bpermute(l0b, (int)b.y);
  const unsigned x2 = __builtin_amdgcn_ds_bpermute(l1b, (int)a.x);
  const unsigned y2 = __builtin_amdgcn_ds_bpermute(l1b, (int)b.x);
  const unsigned x3 = __builtin_amdgcn_ds_bpermute(l1b, (int)a.y);
  const unsigned y3 = __builtin_amdgcn_ds_bpermute(l1b, (int)b.y);
  r.u[0] = hi ? y0 : x0; r.u[1] = hi ? y1 : x1;
  r.u[2] = hi ? y2 : x2; r.u[3] = hi ? y3 : x3;
  return r.v;
}

// ---------- prep (unchanged from r11) ----------
__global__ __launch_bounds__(256)
void prep_kernel(const float* __restrict__ qpw, const float* __restrict__ kpw,
                 const float* __restrict__ vpw, const float* __restrict__ pjw,
                 const float* __restrict__ rpb,
                 const float* __restrict__ qdw, const float* __restrict__ kdw,
                 const float* __restrict__ vdw,
                 const float* __restrict__ qdwb, const float* __restrict__ kdwb,
                 const float* __restrict__ vdwb,
                 ushort* __restrict__ wfrag, float* __restrict__ biasx,
                 unsigned int* __restrict__ dwf, unsigned int* __restrict__ dwb2)
{
  const int idx = blockIdx.x*256 + threadIdx.x;
  if (idx < 8192) {
    const int mat = idx >> 11, rem = idx & 2047;
    const int nt8 = rem >> 8, ks = (rem >> 6) & 3, lane = rem & 63;
    const int c16 = lane & 15, g = lane >> 4;
    const float* Ws[4] = {qpw, kpw, vpw, pjw};
    const float* src = Ws[mat] + (nt8*16 + c16)*128 + ks*32 + g*8;
    ushort* dst = wfrag + idx*8;
    #pragma unroll
    for (int e = 0; e < 8; ++e) dst[e] = f2h(src[e]);
  } else if (idx < 24576) {
    const int i2 = idx - 8192;
    const int he = i2 >> 12;
    const int m2 = (i2 >> 10) & 3;
    const int n  = (i2 >> 4) & 63;
    const int gr = i2 & 15;
    const int m  = m2*16 + gr;
    const int ny = n >> 3, nx = n & 7, my = m >> 3, mx = m & 7;
    biasx[i2] = rpb[((ny - my + 7)*15 + (nx - mx + 7))*4 + he];
  } else if (idx < 24576 + 2304) {
    const int i2 = idx - 24576;
    const int p = i2 / 768, rem = i2 % 768, cp = rem / 12, j = rem % 12;
    const float* dws[3] = {qdw, kdw, vdw};
    unsigned int v = 0;
    if (j < 9) v = pkh(dws[p][(2*cp)*9 + j], dws[p][(2*cp+1)*9 + j]);
    dwf[(p*64 + cp)*12 + j] = v;
  } else if (idx < 24576 + 2304 + 192) {
    const int i2 = idx - 24576 - 2304;
    const int p = i2 >> 6, cp = i2 & 63;
    const float* dbs[3] = {qdwb, kdwb, vdwb};
    dwb2[p*64 + cp] = pkh(dbs[p][2*cp], dbs[p][2*cp+1]);
  }
}

// ---------- main: fused v3 (32 KB LDS, 6 barriers, X_v in regs) ----------
__global__ __launch_bounds__(512, 8)
void winattn_v3(const float* __restrict__ vid,
                const float* __restrict__ qpwb, const float* __restrict__ kpwb,
                const float* __restrict__ vpwb, const float* __restrict__ pjb,
                const ushort* __restrict__ wfrag, const float* __restrict__ biasx,
                const unsigned int* __restrict__ dwf, const unsigned int* __restrict__ dwb2,
                float* __restrict__ out)
{
  __shared__ __attribute__((aligned(16))) char smem[SMEM_SZ];
  char* t0 = smem;            // X_q, then X_v, then V^T [128 d][128B]
  char* t1 = smem + 16384;    // X_k, then K, then O

  const int tid  = threadIdx.x;
  const int w    = tid >> 6;
  const int lane = tid & 63;
  const int g    = lane >> 4;
  const int c16  = lane & 15;
  const int hi   = (lane >= 32);
  const int l0b  = (((g & 1) << 5) + c16) << 2;   // bpermute byte index
  const int l1b  = l0b + 64;

  // XCD-aware bijective swizzle (4608 % 8 == 0)
  const int wid = (blockIdx.x & 7) * (NWIN_ / 8) + (blockIdx.x >> 3);
  const int t  = wid / (HN_*WN_);
  const int hw = wid % (HN_*WN_);
  const int hn = hw / WN_, wn = hw % WN_;
  const int h0 = hn*8, w0 = wn*8;

  const int mt  = w & 3;
  const int ntb = (w >> 2) * 4;
  const int n0  = mt*16 + g*4;
  const int he = w >> 1, half = w & 1;
  const int y = w;

  // ---- phase 0: conv q->t0, conv k->t1, conv v->xv8 regs (hx dies here) ----
  unsigned int xv8[8];
  {
    __half2 hx[3][10];
    #pragma unroll
    for (int dy = 0; dy < 3; ++dy){
      const int hh = h0 + y - 1 + dy;
      const bool rv = (unsigned)hh < (unsigned)H_;
      #pragma unroll
      for (int xc = 0; xc < 10; ++xc){
        const int ww = w0 - 1 + xc;
        float2 l = make_float2(0.f, 0.f);
        if (rv && (unsigned)ww < (unsigned)W_)
          l = *reinterpret_cast<const float2*>(&vid[(((long)t*H_ + hh)*W_ + ww)*C_ + 2*lane]);
        hx[dy][xc] = __float22half2_rn(l);
      }
    }
    #pragma unroll
    for (int p = 0; p < 3; ++p){
      const uint4* dq = reinterpret_cast<const uint4*>(dwf + (p*64 + lane)*12);
      const uint4 wA = dq[0], wB = dq[1], wC = dq[2];
      const __half2 w9[9] = { u2h(wA.x), u2h(wA.y), u2h(wA.z), u2h(wA.w),
                              u2h(wB.x), u2h(wB.y), u2h(wB.z), u2h(wB.w), u2h(wC.x) };
      const __half2 b2 = u2h(dwb2[p*64 + lane]);
      __half2 acc[8];
      #pragma unroll
      for (int px = 0; px < 8; ++px) acc[px] = b2;
      #pragma unroll
      for (int dy = 0; dy < 3; ++dy)
        #pragma unroll
        for (int dx = 0; dx < 3; ++dx){
          const __half2 w2 = w9[dy*3+dx];
          #pragma unroll
          for (int px = 0; px < 8; ++px)
            acc[px] = __hfma2(hx[dy][px+dx], w2, acc[px]);
        }
      if (p == 0){
        #pragma unroll
        for (int px = 0; px < 8; ++px)
          *reinterpret_cast<unsigned int*>(t0 + swz256(y*8+px, 4*lane)) = relu2u(acc[px]);
      } else if (p == 1){
        #pragma unroll
        for (int px = 0; px < 8; ++px)
          *reinterpret_cast<unsigned int*>(t1 + swz256(y*8+px, 4*lane)) = relu2u(acc[px]);
      } else {
        #pragma unroll
        for (int px = 0; px < 8; ++px)
          xv8[px] = relu2u(acc[px]);
      }
    }
  }
  __syncthreads();   // (1) X_q, X_k visible

  // ---- Q: swapped-operand GEMM (A=W-frags, B=X_q token-frags) -> qfrag regs ----
  f16x8 qfrag[2];
  {
    uint2 pkq[2][2];
    #pragma unroll
    for (int dt = 0; dt < 2; ++dt){
      f32x4 aq[2] = {{0.f,0.f,0.f,0.f},{0.f,0.f,0.f,0.f}};
      #pragma unroll
      for (int ks = 0; ks < 4; ++ks){
        const f16x8 awf = *reinterpret_cast<const f16x8*>(&wfrag[(((he*2+dt)*4 + ks)*64 + lane)*8]);
        #pragma unroll
        for (int qt = 0; qt < 2; ++qt){
          const f16x8 btf = *reinterpret_cast<const f16x8*>(t0 + swz256(half*32+qt*16+c16, ks*64 + g*16));
          aq[qt] = __builtin_amdgcn_mfma_f32_16x16x32_f16(awf, btf, aq[qt], 0, 0, 0);
        }
      }
      const float4 qb4 = *reinterpret_cast<const float4*>(&qpwb[he*32 + dt*16 + g*4]);
      #pragma unroll
      for (int qt = 0; qt < 2; ++qt){
        pkq[dt][qt] = make_uint2(pkh((aq[qt][0]+qb4.x)*SCALE_, (aq[qt][1]+qb4.y)*SCALE_),
                                 pkh((aq[qt][2]+qb4.z)*SCALE_, (aq[qt][3]+qb4.w)*SCALE_));
      }
    }
    #pragma unroll
    for (int qt = 0; qt < 2; ++qt)
      qfrag[qt] = xpose_frag(pkq[0][qt], pkq[1][qt], l0b, l1b, hi);
  }
  __syncthreads();   // (2) X_q reads done -> t0 reusable

  // ---- store X_v -> t0 ; K GEMM (A from X_k=t1) -> K packed regs ----
  #pragma unroll
  for (int px = 0; px < 8; ++px)
    *reinterpret_cast<unsigned int*>(t0 + swz256(y*8+px, 4*lane)) = xv8[px];
  unsigned int ku[8];
  {
    const ushort* wp = wfrag + 16384;
    f16x8 kaf[4];
    #pragma unroll
    for (int ks = 0; ks < 4; ++ks)
      kaf[ks] = *reinterpret_cast<const f16x8*>(t1 + swz256(mt*16+c16, ks*64 + g*16));
    #pragma unroll
    for (int nh = 0; nh < 2; ++nh){
      f32x4 a2[2] = {{0.f,0.f,0.f,0.f},{0.f,0.f,0.f,0.f}};
      #pragma unroll
      for (int ks = 0; ks < 4; ++ks){
        #pragma unroll
        for (int j = 0; j < 2; ++j){
          const f16x8 bf = *reinterpret_cast<const f16x8*>(&wp[(((ntb+nh*2+j)*4 + ks)*64 + lane)*8]);
          a2[j] = __builtin_amdgcn_mfma_f32_16x16x32_f16(kaf[ks], bf, a2[j], 0, 0, 0);
        }
      }
      #pragma unroll
      for (int j = 0; j < 2; ++j){
        const float bias = kpwb[(ntb+nh*2+j)*16 + c16];
        ku[(nh*2+j)*2+0] = pkh(a2[j][0]+bias, a2[j][1]+bias);
        ku[(nh*2+j)*2+1] = pkh(a2[j][2]+bias, a2[j][3]+bias);
      }
    }
  }
  __syncthreads();   // (3) X_v visible in t0; X_k reads done -> t1 reusable

  // ---- store K -> t1 ; V GEMM (A from X_v=t0) -> V^T packed regs ----
  #pragma unroll
  for (int q4 = 0; q4 < 4; ++q4){
    const int co = (ntb+q4)*16 + c16;
    *reinterpret_cast<ushort*>(t1 + swz256(n0+0, 2*co)) = (ushort)ku[q4*2+0];
    *reinterpret_cast<ushort*>(t1 + swz256(n0+1, 2*co)) = (ushort)(ku[q4*2+0] >> 16);
    *reinterpret_cast<ushort*>(t1 + swz256(n0+2, 2*co)) = (ushort)ku[q4*2+1];
    *reinterpret_cast<ushort*>(t1 + swz256(n0+3, 2*co)) = (ushort)(ku[q4*2+1] >> 16);
  }
  uint2 vtr[4];
  {
    const ushort* wp = wfrag + 2*16384;
    f16x8 vaf[4];
    #pragma unroll
    for (int ks = 0; ks < 4; ++ks)
      vaf[ks] = *reinterpret_cast<const f16x8*>(t0 + swz256(mt*16+c16, ks*64 + g*16));
    #pragma unroll
    for (int nh = 0; nh < 2; ++nh){
      f32x4 a2[2] = {{0.f,0.f,0.f,0.f},{0.f,0.f,0.f,0.f}};
      #pragma unroll
      for (int ks = 0; ks < 4; ++ks){
        #pragma unroll
        for (int j = 0; j < 2; ++j){
          const f16x8 bf = *reinterpret_cast<const f16x8*>(&wp[(((ntb+nh*2+j)*4 + ks)*64 + lane)*8]);
          a2[j] = __builtin_amdgcn_mfma_f32_16x16x32_f16(vaf[ks], bf, a2[j], 0, 0, 0);
        }
      }
      #pragma unroll
      for (int j = 0; j < 2; ++j){
        const float bias = vpwb[(ntb+nh*2+j)*16 + c16];
        vtr[nh*2+j] = make_uint2(pkh(a2[j][0]+bias, a2[j][1]+bias),
                                 pkh(a2[j][2]+bias, a2[j][3]+bias));
      }
    }
  }
  __syncthreads();   // (4) K visible in t1; X_v reads done -> t0 reusable

  // ---- store V^T -> t0 ; QK^T (swapped: A=K, B=Q) + softmax -> pf regs ----
  #pragma unroll
  for (int nt = 0; nt < 4; ++nt)
    *reinterpret_cast<uint2*>(t0 + swz128((ntb+nt)*16 + c16, 2*n0)) = vtr[nt];
  f16x8 pf[2][2];
  #pragma unroll
  for (int qt = 0; qt < 2; ++qt){
    f32x4 st[4];
    #pragma unroll
    for (int m2 = 0; m2 < 4; ++m2){
      const f16x8 kf = *reinterpret_cast<const f16x8*>(t1 + swz256(m2*16 + c16, he*64 + g*16));
      const f32x4 z = {0.f,0.f,0.f,0.f};
      st[m2] = __builtin_amdgcn_mfma_f32_16x16x32_f16(kf, qfrag[qt], z, 0, 0, 0);
    }
    const int n = half*32 + qt*16 + c16;
    float mx = -1e30f;
    #pragma unroll
    for (int m2 = 0; m2 < 4; ++m2){
      const float4 bx = *reinterpret_cast<const float4*>(&biasx[(((he*4+m2)*64 + n) << 4) + (g << 2)]);
      st[m2][0] += bx.x; st[m2][1] += bx.y; st[m2][2] += bx.z; st[m2][3] += bx.w;
      mx = fmaxf(mx, fmaxf(fmaxf(st[m2][0], st[m2][1]), fmaxf(st[m2][2], st[m2][3])));
    }
    mx = fmaxf(mx, __shfl_xor(mx, 16));
    mx = fmaxf(mx, __shfl_xor(mx, 32));
    float ls = 0.f;
    #pragma unroll
    for (int m2 = 0; m2 < 4; ++m2){
      #pragma unroll
      for (int r = 0; r < 4; ++r){
        st[m2][r] = __expf(st[m2][r] - mx);
        ls += st[m2][r];
      }
    }
    ls += __shfl_xor(ls, 16);
    ls += __shfl_xor(ls, 32);
    const float inv = 1.0f / ls;
    uint2 pk[4];
    #pragma unroll
    for (int m2 = 0; m2 < 4; ++m2)
      pk[m2] = make_uint2(pkh(st[m2][0]*inv, st[m2][1]*inv),
                          pkh(st[m2][2]*inv, st[m2][3]*inv));
    #pragma unroll
    for (int ks = 0; ks < 2; ++ks)
      pf[qt][ks] = xpose_frag(pk[2*ks], pk[2*ks+1], l0b, l1b, hi);
  }
  __syncthreads();   // (5) V^T visible in t0; K reads done -> t1 reusable

  // ---- PV: O = P @ V (A=P regs, B=V^T in t0) -> O into t1 ----
  {
    f32x4 o[2][2];
    #pragma unroll
    for (int qt = 0; qt < 2; ++qt)
      #pragma unroll
      for (int dt = 0; dt < 2; ++dt) o[qt][dt] = (f32x4){0.f,0.f,0.f,0.f};
    #pragma unroll
    for (int ks = 0; ks < 2; ++ks){
      #pragma unroll
      for (int dt = 0; dt < 2; ++dt){
        const f16x8 vf = *reinterpret_cast<const f16x8*>(t0 + swz128(he*32+dt*16+c16, ks*64 + g*16));
        #pragma unroll
        for (int qt = 0; qt < 2; ++qt)
          o[qt][dt] = __builtin_amdgcn_mfma_f32_16x16x32_f16(pf[qt][ks], vf, o[qt][dt], 0, 0, 0);
      }
    }
    #pragma unroll
    for (int qt = 0; qt < 2; ++qt)
      #pragma unroll
      for (int dt = 0; dt < 2; ++dt){
        const int d2 = he*32 + dt*16 + c16;
        const int nb = half*32 + qt*16 + g*4;
        const unsigned int u01 = pkh(o[qt][dt][0], o[qt][dt][1]);
        const unsigned int u23 = pkh(o[qt][dt][2], o[qt][dt][3]);
        *reinterpret_cast<ushort*>(t1 + swz256(nb+0, 2*d2)) = (ushort)u01;
        *reinterpret_cast<ushort*>(t1 + swz256(nb+1, 2*d2)) = (ushort)(u01 >> 16);
        *reinterpret_cast<ushort*>(t1 + swz256(nb+2, 2*d2)) = (ushort)u23;
        *reinterpret_cast<ushort*>(t1 + swz256(nb+3, 2*d2)) = (ushort)(u23 >> 16);
      }
  }
  __syncthreads();   // (6) O visible in t1

  // ---- projection GEMM + output ----
  {
    const ushort* wp = wfrag + 3*16384;
    #pragma unroll
    for (int nh = 0; nh < 2; ++nh){
      f32x4 a2[2] = {{0.f,0.f,0.f,0.f},{0.f,0.f,0.f,0.f}};
      #pragma unroll
      for (int ks = 0; ks < 4; ++ks){
        const f16x8 af = *reinterpret_cast<const f16x8*>(t1 + swz256(mt*16+c16, ks*64 + g*16));
        #pragma unroll
        for (int j = 0; j < 2; ++j){
          const f16x8 bf = *reinterpret_cast<const f16x8*>(&wp[(((ntb+nh*2+j)*4 + ks)*64 + lane)*8]);
          a2[j] = __builtin_amdgcn_mfma_f32_16x16x32_f16(af, bf, a2[j], 0, 0, 0);
        }
      }
      #pragma unroll
      for (int j = 0; j < 2; ++j){
        const int co = (ntb+nh*2+j)*16 + c16;
        const float bias = pjb[co];
        #pragma unroll
        for (int r = 0; r < 4; ++r){
          const int n = n0 + r;
          out[(((long)t*H_ + (h0+(n>>3)))*W_ + (w0+(n&7)))*C_ + co] = a2[j][r] + bias;
        }
      }
    }
  }
}

extern "C" void kernel_launch(void* const* d_in, const int* in_sizes, int n_in,
                              void* d_out, int out_size, void* d_ws, size_t ws_size,
                              hipStream_t stream) {
  const float* vid  = (const float*)d_in[0];
  const float* rpb  = (const float*)d_in[1];
  const float* qdw  = (const float*)d_in[2];
  const float* qdwb = (const float*)d_in[3];
  const float* qpw  = (const float*)d_in[4];
  const float* qpwb = (const float*)d_in[5];
  const float* kdw  = (const float*)d_in[6];
  const float* kdwb = (const float*)d_in[7];
  const float* kpw  = (const float*)d_in[8];
  const float* kpwb = (const float*)d_in[9];
  const float* vdw  = (const float*)d_in[10];
  const float* vdwb = (const float*)d_in[11];
  const float* vpw  = (const float*)d_in[12];
  const float* vpwb = (const float*)d_in[13];
  const float* pjw  = (const float*)d_in[14];
  const float* pjb  = (const float*)d_in[15];
  float* outp = (float*)d_out;

  ushort*       wfrag = (ushort*)((char*)d_ws + WS_WFRAG);
  float*        biasx = (float*)((char*)d_ws + WS_BIASX);
  unsigned int* dwf   = (unsigned int*)((char*)d_ws + WS_DWF);
  unsigned int* dwb2  = (unsigned int*)((char*)d_ws + WS_DWB);

  prep_kernel<<<dim3(106), dim3(256), 0, stream>>>(
      qpw, kpw, vpw, pjw, rpb, qdw, kdw, vdw, qdwb, kdwb, vdwb,
      wfrag, biasx, dwf, dwb2);
  winattn_v3<<<dim3(NWIN_), dim3(512), 0, stream>>>(
      vid, qpwb, kpwb, vpwb, pjb, wfrag, biasx, dwf, dwb2, outp);
}

// Round 13
// 179.956 us; speedup vs baseline: 2.0781x; 2.0781x over previous
//
#include <hip/hip_runtime.h>
#include <hip/hip_fp16.h>
#include <stdint.h>

#define T_ 2
#define H_ 384
#define W_ 384
#define C_ 128
#define HN_ 48
#define WN_ 48
#define NWIN_ (T_*HN_*WN_)
#define SCALE_ 0.17677669529663687f

typedef float f32x4 __attribute__((ext_vector_type(4)));
typedef _Float16 f16x8 __attribute__((ext_vector_type(8)));

// ---- workspace ----
#define WS_WFRAG 0        // 4 mats x [nt8][ks][lane][8] f16 = 131072 B (fragment-linear)
#define WS_BIASX 131072   // [he][n][c16][m2] f32 = 65536 B
#define WS_DWF   196608   // [3][64 cp][12] half2-as-uint = 9216 B
#define WS_DWB   205824   // [3][64 cp] half2-as-uint = 768 B

// ---- LDS: 80 KB ----
// tmp[64 tok][256B f16] (overlay: vt[128 d][128B]) | q | k | W(32KB staged weights)
#define TMP_OFF 0
#define Q_OFF   16384
#define K_OFF   32768
#define W_OFF   49152
#define SMEM_SZ 81920

#define GLOBAL_AS __attribute__((address_space(1)))
#define LDS_AS    __attribute__((address_space(3)))

__device__ __forceinline__ void g2l16(const void* g, void* l){
  __builtin_amdgcn_global_load_lds((const GLOBAL_AS unsigned int*)g,
                                   (LDS_AS unsigned int*)l, 16, 0, 0);
}

__device__ __forceinline__ unsigned int pkh(float a, float b){
  union{__half2 h; unsigned int u;} c;
  c.h = __float22half2_rn(make_float2(a, b));
  return c.u;
}
__device__ __forceinline__ unsigned short f2h(float f){
  union{__half h; unsigned short u;} c; c.h = __float2half_rn(f); return c.u;
}
__device__ __forceinline__ __half2 u2h(unsigned int u){
  union{unsigned int u; __half2 h;} c; c.u = u; return c.h;
}
// packed-half ReLU via sign-mask (exact for non-NaN)
__device__ __forceinline__ unsigned int relu2u(__half2 v){
  union{__half2 h; unsigned int u;} c; c.h = v;
  const unsigned int m = ((c.u >> 15) & 0x00010001u) * 0xFFFFu;
  return c.u & ~m;
}
__device__ __forceinline__ int swz256(int row, int b){ return row*256 + (b ^ ((row & 15) << 4)); }
__device__ __forceinline__ int swz128(int row, int b){ return row*128 + (b ^ ((row & 7) << 4)); }

// ---------- prep: weights -> f16 fragment-linear; rpb -> expanded bias; dw packed ----------
__global__ __launch_bounds__(256)
void prep_kernel(const float* __restrict__ qpw, const float* __restrict__ kpw,
                 const float* __restrict__ vpw, const float* __restrict__ pjw,
                 const float* __restrict__ rpb,
                 const float* __restrict__ qdw, const float* __restrict__ kdw,
                 const float* __restrict__ vdw,
                 const float* __restrict__ qdwb, const float* __restrict__ kdwb,
                 const float* __restrict__ vdwb,
                 ushort* __restrict__ wfrag, float* __restrict__ biasx,
                 unsigned int* __restrict__ dwf, unsigned int* __restrict__ dwb2)
{
  const int idx = blockIdx.x*256 + threadIdx.x;
  if (idx < 8192) {
    const int mat = idx >> 11, rem = idx & 2047;
    const int nt8 = rem >> 8, ks = (rem >> 6) & 3, lane = rem & 63;
    const int c16 = lane & 15, g = lane >> 4;
    const float* Ws[4] = {qpw, kpw, vpw, pjw};
    const float* src = Ws[mat] + (nt8*16 + c16)*128 + ks*32 + g*8;
    ushort* dst = wfrag + idx*8;
    #pragma unroll
    for (int e = 0; e < 8; ++e) dst[e] = f2h(src[e]);
  } else if (idx < 24576) {
    const int i2 = idx - 8192;
    const int he = i2 >> 12, n = (i2 >> 6) & 63, m = i2 & 63;
    const int ny = n >> 3, nx = n & 7, my = m >> 3, mx = m & 7;
    biasx[((he*64 + n)*16 + (m & 15))*4 + (m >> 4)] =
        rpb[((ny - my + 7)*15 + (nx - mx + 7))*4 + he];
  } else if (idx < 24576 + 2304) {
    const int i2 = idx - 24576;
    const int p = i2 / 768, rem = i2 % 768, cp = rem / 12, j = rem % 12;
    const float* dws[3] = {qdw, kdw, vdw};
    unsigned int v = 0;
    if (j < 9) v = pkh(dws[p][(2*cp)*9 + j], dws[p][(2*cp+1)*9 + j]);
    dwf[(p*64 + cp)*12 + j] = v;
  } else if (idx < 24576 + 2304 + 192) {
    const int i2 = idx - 24576 - 2304;
    const int p = i2 >> 6, cp = i2 & 63;
    const float* dbs[3] = {qdwb, kdwb, vdwb};
    dwb2[p*64 + cp] = pkh(dbs[p][2*cp], dbs[p][2*cp+1]);
  }
}

// ---------- main: r6 structure + LDS-staged weights (global_load_lds) ----------
__global__ __launch_bounds__(512, 8)
void winattn_mfma8(const float* __restrict__ vid,
                   const float* __restrict__ qpwb, const float* __restrict__ kpwb,
                   const float* __restrict__ vpwb, const float* __restrict__ pjb,
                   const ushort* __restrict__ wfrag, const float* __restrict__ biasx,
                   const unsigned int* __restrict__ dwf, const unsigned int* __restrict__ dwb2,
                   float* __restrict__ out)
{
  __shared__ __attribute__((aligned(16))) char smem[SMEM_SZ];
  char* tmpb = smem + TMP_OFF;   // tmp (256B rows) / vt (128B rows)
  char* qb   = smem + Q_OFF;     // q / P rows 0-255 (spans q+k) / O
  char* kb   = smem + K_OFF;     // k
  char* wl   = smem + W_OFF;     // staged weight matrix (32KB, fragment-linear)

  const int tid  = threadIdx.x;
  const int w    = tid >> 6;
  const int lane = tid & 63;
  const int g    = lane >> 4;
  const int c16  = lane & 15;

  // async-stage one 32KB weight matrix into wl (no VGPR cost; drained by next barrier)
  auto stage_w = [&](int m){
    const char* gsrc = reinterpret_cast<const char*>(wfrag) + m*32768;
    #pragma unroll
    for (int i2 = 0; i2 < 4; ++i2){
      const int off = (i2*512 + tid)*16;
      g2l16(gsrc + off, wl + off);
    }
  };

  // XCD-aware bijective swizzle (4608 % 8 == 0)
  const int wid = (blockIdx.x & 7) * (NWIN_ / 8) + (blockIdx.x >> 3);
  const int t  = wid / (HN_*WN_);
  const int hw = wid % (HN_*WN_);
  const int hn = hw / WN_, wn = hw % WN_;
  const int h0 = hn*8, w0 = wn*8;

  stage_w(0);   // W_q flies under halo load + conv

  // ---- input halo -> packed f16 registers (wave = row y, lane = channel pair) ----
  const int y = w;
  __half2 hx[3][10];
  #pragma unroll
  for (int dy = 0; dy < 3; ++dy){
    const int hh = h0 + y - 1 + dy;
    const bool rv = (unsigned)hh < (unsigned)H_;
    #pragma unroll
    for (int xc = 0; xc < 10; ++xc){
      const int ww = w0 - 1 + xc;
      float2 l = make_float2(0.f, 0.f);
      if (rv && (unsigned)ww < (unsigned)W_)
        l = *reinterpret_cast<const float2*>(&vid[(((long)t*H_ + hh)*W_ + ww)*C_ + 2*lane]);
      hx[dy][xc] = __float22half2_rn(l);
    }
  }

  const int mt  = w & 3;
  const int ntb = (w >> 2) * 4;
  const int n0  = mt*16 + g*4;

  #pragma unroll
  for (int p = 0; p < 3; ++p) {
    if (p > 0) stage_w(p);   // previous GEMM's W reads finished at trailing barrier
    // ---- depthwise 3x3 + bias + relu, packed f16 ----
    {
      const uint4* dq = reinterpret_cast<const uint4*>(dwf + (p*64 + lane)*12);
      const uint4 wA = dq[0], wB = dq[1], wC = dq[2];
      const __half2 w9[9] = { u2h(wA.x), u2h(wA.y), u2h(wA.z), u2h(wA.w),
                              u2h(wB.x), u2h(wB.y), u2h(wB.z), u2h(wB.w), u2h(wC.x) };
      const __half2 b2 = u2h(dwb2[p*64 + lane]);
      __half2 acc[8];
      #pragma unroll
      for (int px = 0; px < 8; ++px) acc[px] = b2;
      #pragma unroll
      for (int dy = 0; dy < 3; ++dy)
        #pragma unroll
        for (int dx = 0; dx < 3; ++dx){
          const __half2 w2 = w9[dy*3+dx];
          #pragma unroll
          for (int px = 0; px < 8; ++px)
            acc[px] = __hfma2(hx[dy][px+dx], w2, acc[px]);
        }
      #pragma unroll
      for (int px = 0; px < 8; ++px)
        *reinterpret_cast<unsigned int*>(tmpb + swz256(y*8+px, 4*lane)) = relu2u(acc[px]);
    }
    __syncthreads();   // tmp visible; W_p staging drained (vmcnt(0) before barrier)
    // ---- pointwise GEMM: Y[64,128] = X @ W^T (B-frags from LDS wl) ----
    const float scl = (p == 0) ? SCALE_ : 1.0f;
    if (p < 2) {
      char* dst = (p == 0) ? qb : kb;
      const float* pwb = (p == 0) ? qpwb : kpwb;
      #pragma unroll
      for (int nh = 0; nh < 2; ++nh){
        f32x4 a2[2] = {{0.f,0.f,0.f,0.f},{0.f,0.f,0.f,0.f}};
        #pragma unroll
        for (int ks = 0; ks < 4; ++ks){
          const f16x8 af = *reinterpret_cast<const f16x8*>(tmpb + swz256(mt*16+c16, ks*64 + g*16));
          #pragma unroll
          for (int j = 0; j < 2; ++j){
            const f16x8 bf = *reinterpret_cast<const f16x8*>(wl + (((ntb+nh*2+j)*4 + ks)*64 + lane)*16);
            a2[j] = __builtin_amdgcn_mfma_f32_16x16x32_f16(af, bf, a2[j], 0, 0, 0);
          }
        }
        #pragma unroll
        for (int j = 0; j < 2; ++j){
          const int co = (ntb+nh*2+j)*16 + c16;
          const float bias = pwb[co];
          const unsigned int u01 = pkh((a2[j][0]+bias)*scl, (a2[j][1]+bias)*scl);
          const unsigned int u23 = pkh((a2[j][2]+bias)*scl, (a2[j][3]+bias)*scl);
          *reinterpret_cast<ushort*>(dst + swz256(n0+0, 2*co)) = (ushort)u01;
          *reinterpret_cast<ushort*>(dst + swz256(n0+1, 2*co)) = (ushort)(u01 >> 16);
          *reinterpret_cast<ushort*>(dst + swz256(n0+2, 2*co)) = (ushort)u23;
          *reinterpret_cast<ushort*>(dst + swz256(n0+3, 2*co)) = (ushort)(u23 >> 16);
        }
      }
      __syncthreads();   // tmp reads + W_p reads done -> next p may overwrite both
    } else {
      uint2 vtr[4];
      #pragma unroll
      for (int nh = 0; nh < 2; ++nh){
        f32x4 a2[2] = {{0.f,0.f,0.f,0.f},{0.f,0.f,0.f,0.f}};
        #pragma unroll
        for (int ks = 0; ks < 4; ++ks){
          const f16x8 af = *reinterpret_cast<const f16x8*>(tmpb + swz256(mt*16+c16, ks*64 + g*16));
          #pragma unroll
          for (int j = 0; j < 2; ++j){
            const f16x8 bf = *reinterpret_cast<const f16x8*>(wl + (((ntb+nh*2+j)*4 + ks)*64 + lane)*16);
            a2[j] = __builtin_amdgcn_mfma_f32_16x16x32_f16(af, bf, a2[j], 0, 0, 0);
          }
        }
        #pragma unroll
        for (int j = 0; j < 2; ++j){
          const float bias = vpwb[(ntb+nh*2+j)*16 + c16];
          vtr[nh*2+j] = make_uint2(pkh(a2[j][0]+bias, a2[j][1]+bias),
                                   pkh(a2[j][2]+bias, a2[j][3]+bias));
        }
      }
      __syncthreads();   // (C) all tmp reads + W_v reads done
      stage_w(3);        // W_proj flies under attention (drained by barrier D/E/F)
      #pragma unroll
      for (int nt = 0; nt < 4; ++nt)
        *reinterpret_cast<uint2*>(tmpb + swz128((ntb+nt)*16 + c16, 2*n0)) = vtr[nt];
    }
  }

  // ---- attention: wave (he, half) owns 32 query rows of head he ----
  const int he = w >> 1, half = w & 1;
  unsigned int pu[2][4][2];   // packed normalized P (f16 pairs)
  {
    f32x4 S[2][4];
    #pragma unroll
    for (int mi = 0; mi < 2; ++mi){
      const f16x8 qf = *reinterpret_cast<const f16x8*>(qb + swz256((half*2+mi)*16 + c16, he*64 + g*16));
      #pragma unroll
      for (int m2 = 0; m2 < 4; ++m2){
        const f16x8 kf = *reinterpret_cast<const f16x8*>(kb + swz256(m2*16 + c16, he*64 + g*16));
        const f32x4 z = {0.f,0.f,0.f,0.f};
        S[mi][m2] = __builtin_amdgcn_mfma_f32_16x16x32_f16(qf, kf, z, 0, 0, 0);
      }
    }
    #pragma unroll
    for (int mi = 0; mi < 2; ++mi){
      #pragma unroll
      for (int r = 0; r < 4; ++r){
        const int n = (half*2+mi)*16 + g*4 + r;
        const float4 bx = *reinterpret_cast<const float4*>(&biasx[((he*64+n)*16 + c16)*4]);
        float v0 = S[mi][0][r]+bx.x, v1 = S[mi][1][r]+bx.y;
        float v2 = S[mi][2][r]+bx.z, v3 = S[mi][3][r]+bx.w;
        float mx = fmaxf(fmaxf(v0,v1), fmaxf(v2,v3));
        mx = fmaxf(mx, __shfl_xor(mx, 1));
        mx = fmaxf(mx, __shfl_xor(mx, 2));
        mx = fmaxf(mx, __shfl_xor(mx, 4));
        mx = fmaxf(mx, __shfl_xor(mx, 8));
        const float e0 = __expf(v0-mx), e1 = __expf(v1-mx);
        const float e2 = __expf(v2-mx), e3 = __expf(v3-mx);
        float ls = e0+e1+e2+e3;
        ls += __shfl_xor(ls, 1);
        ls += __shfl_xor(ls, 2);
        ls += __shfl_xor(ls, 4);
        ls += __shfl_xor(ls, 8);
        const float inv = 1.0f / ls;
        pu[mi][r][0] = pkh(e0*inv, e1*inv);
        pu[mi][r][1] = pkh(e2*inv, e3*inv);
      }
    }
  }
  __syncthreads();   // (D) V^T writes done; q/k reads done -> P may overlay q+k
  #pragma unroll
  for (int mi = 0; mi < 2; ++mi)
    #pragma unroll
    for (int r = 0; r < 4; ++r){
      const int rr = he*64 + (half*2+mi)*16 + g*4 + r;
      *reinterpret_cast<ushort*>(qb + swz128(rr,  0 + 2*c16)) = (ushort)pu[mi][r][0];
      *reinterpret_cast<ushort*>(qb + swz128(rr, 32 + 2*c16)) = (ushort)(pu[mi][r][0] >> 16);
      *reinterpret_cast<ushort*>(qb + swz128(rr, 64 + 2*c16)) = (ushort)pu[mi][r][1];
      *reinterpret_cast<ushort*>(qb + swz128(rr, 96 + 2*c16)) = (ushort)(pu[mi][r][1] >> 16);
    }
  __syncthreads();   // (E)
  // ---- PV: O = P @ V (A=P overlay, B=V^T in tmp) ----
  {
    f32x4 oacc[2][2];
    #pragma unroll
    for (int mi = 0; mi < 2; ++mi)
      #pragma unroll
      for (int nt = 0; nt < 2; ++nt) oacc[mi][nt] = (f32x4){0.f,0.f,0.f,0.f};
    #pragma unroll
    for (int ks = 0; ks < 2; ++ks){
      #pragma unroll
      for (int nt = 0; nt < 2; ++nt){
        const f16x8 vf = *reinterpret_cast<const f16x8*>(tmpb + swz128(he*32+nt*16+c16, ks*64 + g*16));
        #pragma unroll
        for (int mi = 0; mi < 2; ++mi){
          const f16x8 pf = *reinterpret_cast<const f16x8*>(qb + swz128(he*64+(half*2+mi)*16+c16, ks*64 + g*16));
          oacc[mi][nt] = __builtin_amdgcn_mfma_f32_16x16x32_f16(pf, vf, oacc[mi][nt], 0, 0, 0);
        }
      }
    }
    __syncthreads();   // (F) P reads done -> O may overwrite q region
    #pragma unroll
    for (int mi = 0; mi < 2; ++mi)
      #pragma unroll
      for (int nt = 0; nt < 2; ++nt){
        const int col = he*32 + nt*16 + c16;
        const int nb = (half*2+mi)*16 + g*4;
        const unsigned int u01 = pkh(oacc[mi][nt][0], oacc[mi][nt][1]);
        const unsigned int u23 = pkh(oacc[mi][nt][2], oacc[mi][nt][3]);
        *reinterpret_cast<ushort*>(qb + swz256(nb+0, 2*col)) = (ushort)u01;
        *reinterpret_cast<ushort*>(qb + swz256(nb+1, 2*col)) = (ushort)(u01 >> 16);
        *reinterpret_cast<ushort*>(qb + swz256(nb+2, 2*col)) = (ushort)u23;
        *reinterpret_cast<ushort*>(qb + swz256(nb+3, 2*col)) = (ushort)(u23 >> 16);
      }
  }
  __syncthreads();   // (G)
  // ---- projection GEMM (B-frags from LDS wl) + output ----
  {
    #pragma unroll
    for (int nh = 0; nh < 2; ++nh){
      f32x4 a2[2] = {{0.f,0.f,0.f,0.f},{0.f,0.f,0.f,0.f}};
      #pragma unroll
      for (int ks = 0; ks < 4; ++ks){
        const f16x8 af = *reinterpret_cast<const f16x8*>(qb + swz256(mt*16+c16, ks*64 + g*16));
        #pragma unroll
        for (int j = 0; j < 2; ++j){
          const f16x8 bf = *reinterpret_cast<const f16x8*>(wl + (((ntb+nh*2+j)*4 + ks)*64 + lane)*16);
          a2[j] = __builtin_amdgcn_mfma_f32_16x16x32_f16(af, bf, a2[j], 0, 0, 0);
        }
      }
      #pragma unroll
      for (int j = 0; j < 2; ++j){
        const int co = (ntb+nh*2+j)*16 + c16;
        const float bias = pjb[co];
        #pragma unroll
        for (int r = 0; r < 4; ++r){
          const int n = n0 + r;
          out[(((long)t*H_ + (h0+(n>>3)))*W_ + (w0+(n&7)))*C_ + co] = a2[j][r] + bias;
        }
      }
    }
  }
}

extern "C" void kernel_launch(void* const* d_in, const int* in_sizes, int n_in,
                              void* d_out, int out_size, void* d_ws, size_t ws_size,
                              hipStream_t stream) {
  const float* vid  = (const float*)d_in[0];
  const float* rpb  = (const float*)d_in[1];
  const float* qdw  = (const float*)d_in[2];
  const float* qdwb = (const float*)d_in[3];
  const float* qpw  = (const float*)d_in[4];
  const float* qpwb = (const float*)d_in[5];
  const float* kdw  = (const float*)d_in[6];
  const float* kdwb = (const float*)d_in[7];
  const float* kpw  = (const float*)d_in[8];
  const float* kpwb = (const float*)d_in[9];
  const float* vdw  = (const float*)d_in[10];
  const float* vdwb = (const float*)d_in[11];
  const float* vpw  = (const float*)d_in[12];
  const float* vpwb = (const float*)d_in[13];
  const float* pjw  = (const float*)d_in[14];
  const float* pjb  = (const float*)d_in[15];
  float* outp = (float*)d_out;

  ushort*       wfrag = (ushort*)((char*)d_ws + WS_WFRAG);
  float*        biasx = (float*)((char*)d_ws + WS_BIASX);
  unsigned int* dwf   = (unsigned int*)((char*)d_ws + WS_DWF);
  unsigned int* dwb2  = (unsigned int*)((char*)d_ws + WS_DWB);

  prep_kernel<<<dim3(106), dim3(256), 0, stream>>>(
      qpw, kpw, vpw, pjw, rpb, qdw, kdw, vdw, qdwb, kdwb, vdwb,
      wfrag, biasx, dwf, dwb2);
  winattn_mfma8<<<dim3(NWIN_), dim3(512), 0, stream>>>(
      vid, qpwb, kpwb, vpwb, pjb, wfrag, biasx, dwf, dwb2, outp);
}

// Round 14
// 164.674 us; speedup vs baseline: 2.2710x; 1.0928x over previous
//
#include <hip/hip_runtime.h>
#include <hip/hip_fp16.h>
#include <stdint.h>

#define T_ 2
#define H_ 384
#define W_ 384
#define C_ 128
#define HN_ 48
#define WN_ 48
#define NWIN_ (T_*HN_*WN_)
#define SCALE_ 0.17677669529663687f

typedef float f32x4 __attribute__((ext_vector_type(4)));
typedef _Float16 f16x8 __attribute__((ext_vector_type(8)));

// ---- workspace ----
#define WS_WFRAG 0        // 4 mats x [nt8][ks][lane][8] f16 = 131072 B (fragment-linear)
#define WS_BIASX 131072   // [he][m2][n][gr] f32 = 65536 B (S^T-fragment layout)
#define WS_DWF   196608   // [3][64 cp][12] half2-as-uint = 9216 B
#define WS_DWB   205824   // [3][64 cp] half2-as-uint = 768 B

// ---- LDS: 80 KB ----
// tmp: X_k -> X_v -> X_q -> O | kb: K | vb: V^T[128][128B] | wl: staged weights 32KB
#define TMP_OFF 0
#define KB_OFF  16384
#define VB_OFF  32768
#define WL_OFF  49152
#define SMEM_SZ 81920

#define GLOBAL_AS __attribute__((address_space(1)))
#define LDS_AS    __attribute__((address_space(3)))

__device__ __forceinline__ void g2l16(const void* g, void* l){
  __builtin_amdgcn_global_load_lds((const GLOBAL_AS unsigned int*)g,
                                   (LDS_AS unsigned int*)l, 16, 0, 0);
}

__device__ __forceinline__ unsigned int pkh(float a, float b){
  union{__half2 h; unsigned int u;} c;
  c.h = __float22half2_rn(make_float2(a, b));
  return c.u;
}
__device__ __forceinline__ unsigned short f2h(float f){
  union{__half h; unsigned short u;} c; c.h = __float2half_rn(f); return c.u;
}
__device__ __forceinline__ __half2 u2h(unsigned int u){
  union{unsigned int u; __half2 h;} c; c.u = u; return c.h;
}
// packed-half ReLU via sign-mask (exact for non-NaN)
__device__ __forceinline__ unsigned int relu2u(__half2 v){
  union{__half2 h; unsigned int u;} c; c.h = v;
  const unsigned int m = ((c.u >> 15) & 0x00010001u) * 0xFFFFu;
  return c.u & ~m;
}
__device__ __forceinline__ int swz256(int row, int b){ return row*256 + (b ^ ((row & 15) << 4)); }
__device__ __forceinline__ int swz128(int row, int b){ return row*128 + (b ^ ((row & 7) << 4)); }

// C-frag(col=c16,row=g*4+r, 2 tiles) -> A/B-frag(row=c16,k=g*8+e)  [proven r7/r11]
__device__ __forceinline__ f16x8 xpose_frag(uint2 a, uint2 b, int l0b, int l1b, int hi){
  union{ f16x8 v; unsigned int u[4]; } r;
  const unsigned x0 = __builtin_amdgcn_ds_bpermute(l0b, (int)a.x);
  const unsigned y0 = __builtin_amdgcn_ds_bpermute(l0b, (int)b.x);
  const unsigned x1 = __builtin_amdgcn_ds_bpermute(l0b, (int)a.y);
  const unsigned y1 = __builtin_amdgcn_ds_bpermute(l0b, (int)b.y);
  const unsigned x2 = __builtin_amdgcn_ds_bpermute(l1b, (int)a.x);
  const unsigned y2 = __builtin_amdgcn_ds_bpermute(l1b, (int)b.x);
  const unsigned x3 = __builtin_amdgcn_ds_bpermute(l1b, (int)a.y);
  const unsigned y3 = __builtin_amdgcn_ds_bpermute(l1b, (int)b.y);
  r.u[0] = hi ? y0 : x0; r.u[1] = hi ? y1 : x1;
  r.u[2] = hi ? y2 : x2; r.u[3] = hi ? y3 : x3;
  return r.v;
}

// ---------- prep: weights -> f16 fragment-linear; rpb -> S^T-layout bias; dw packed ----------
__global__ __launch_bounds__(256)
void prep_kernel(const float* __restrict__ qpw, const float* __restrict__ kpw,
                 const float* __restrict__ vpw, const float* __restrict__ pjw,
                 const float* __restrict__ rpb,
                 const float* __restrict__ qdw, const float* __restrict__ kdw,
                 const float* __restrict__ vdw,
                 const float* __restrict__ qdwb, const float* __restrict__ kdwb,
                 const float* __restrict__ vdwb,
                 ushort* __restrict__ wfrag, float* __restrict__ biasx,
                 unsigned int* __restrict__ dwf, unsigned int* __restrict__ dwb2)
{
  const int idx = blockIdx.x*256 + threadIdx.x;
  if (idx < 8192) {
    const int mat = idx >> 11, rem = idx & 2047;
    const int nt8 = rem >> 8, ks = (rem >> 6) & 3, lane = rem & 63;
    const int c16 = lane & 15, g = lane >> 4;
    const float* Ws[4] = {qpw, kpw, vpw, pjw};
    const float* src = Ws[mat] + (nt8*16 + c16)*128 + ks*32 + g*8;
    ushort* dst = wfrag + idx*8;
    #pragma unroll
    for (int e = 0; e < 8; ++e) dst[e] = f2h(src[e]);
  } else if (idx < 24576) {
    // bias in S^T fragment layout: i2 = ((he*4+m2)*64+n)*16 + g*4 + r
    const int i2 = idx - 8192;
    const int he = i2 >> 12;
    const int m2 = (i2 >> 10) & 3;
    const int n  = (i2 >> 4) & 63;
    const int gr = i2 & 15;
    const int m  = m2*16 + gr;
    const int ny = n >> 3, nx = n & 7, my = m >> 3, mx = m & 7;
    biasx[i2] = rpb[((ny - my + 7)*15 + (nx - mx + 7))*4 + he];
  } else if (idx < 24576 + 2304) {
    const int i2 = idx - 24576;
    const int p = i2 / 768, rem = i2 % 768, cp = rem / 12, j = rem % 12;
    const float* dws[3] = {qdw, kdw, vdw};
    unsigned int v = 0;
    if (j < 9) v = pkh(dws[p][(2*cp)*9 + j], dws[p][(2*cp+1)*9 + j]);
    dwf[(p*64 + cp)*12 + j] = v;
  } else if (idx < 24576 + 2304 + 192) {
    const int i2 = idx - 24576 - 2304;
    const int p = i2 >> 6, cp = i2 & 63;
    const float* dbs[3] = {qdwb, kdwb, vdwb};
    dwb2[p*64 + cp] = pkh(dbs[p][2*cp], dbs[p][2*cp+1]);
  }
}

// ---------- main: K->V->Q phase order, 7 barriers, LDS-staged weights ----------
__global__ __launch_bounds__(512, 8)
void winattn_v4(const float* __restrict__ vid,
                const float* __restrict__ qpwb, const float* __restrict__ kpwb,
                const float* __restrict__ vpwb, const float* __restrict__ pjb,
                const ushort* __restrict__ wfrag, const float* __restrict__ biasx,
                const unsigned int* __restrict__ dwf, const unsigned int* __restrict__ dwb2,
                float* __restrict__ out)
{
  __shared__ __attribute__((aligned(16))) char smem[SMEM_SZ];
  char* tmpb = smem + TMP_OFF;   // X_k / X_v / X_q / O (sequential reuse)
  char* kb   = smem + KB_OFF;    // K [64 tok][256B]
  char* vb   = smem + VB_OFF;    // V^T [128 d][128B]
  char* wl   = smem + WL_OFF;    // staged weight matrix (32KB, fragment-linear)

  const int tid  = threadIdx.x;
  const int w    = tid >> 6;
  const int lane = tid & 63;
  const int g    = lane >> 4;
  const int c16  = lane & 15;
  const int hi   = (lane >= 32);
  const int l0b  = (((g & 1) << 5) + c16) << 2;
  const int l1b  = l0b + 64;

  // async-stage one 32KB weight matrix into wl (no VGPR cost)
  auto stage_w = [&](int m){
    const char* gsrc = reinterpret_cast<const char*>(wfrag) + m*32768;
    #pragma unroll
    for (int i2 = 0; i2 < 4; ++i2){
      const int off = (i2*512 + tid)*16;
      g2l16(gsrc + off, wl + off);
    }
  };

  // XCD-aware bijective swizzle (4608 % 8 == 0)
  const int wid = (blockIdx.x & 7) * (NWIN_ / 8) + (blockIdx.x >> 3);
  const int t  = wid / (HN_*WN_);
  const int hw = wid % (HN_*WN_);
  const int hn = hw / WN_, wn = hw % WN_;
  const int h0 = hn*8, w0 = wn*8;

  const int mt  = w & 3;
  const int ntb = (w >> 2) * 4;
  const int n0  = mt*16 + g*4;
  const int he = w >> 1, half = w & 1;
  const int y = w;

  stage_w(1);   // W_k flies under halo load + conv_k

  // ---- input halo -> packed f16 registers (shared by all 3 convs) ----
  __half2 hx[3][10];
  #pragma unroll
  for (int dy = 0; dy < 3; ++dy){
    const int hh = h0 + y - 1 + dy;
    const bool rv = (unsigned)hh < (unsigned)H_;
    #pragma unroll
    for (int xc = 0; xc < 10; ++xc){
      const int ww = w0 - 1 + xc;
      float2 l = make_float2(0.f, 0.f);
      if (rv && (unsigned)ww < (unsigned)W_)
        l = *reinterpret_cast<const float2*>(&vid[(((long)t*H_ + hh)*W_ + ww)*C_ + 2*lane]);
      hx[dy][xc] = __float22half2_rn(l);
    }
  }

  // depthwise pass p (reads hx regs, writes tmpb)
  auto dw_pass = [&](int p){
    const uint4* dq = reinterpret_cast<const uint4*>(dwf + (p*64 + lane)*12);
    const uint4 wA = dq[0], wB = dq[1], wC = dq[2];
    const __half2 w9[9] = { u2h(wA.x), u2h(wA.y), u2h(wA.z), u2h(wA.w),
                            u2h(wB.x), u2h(wB.y), u2h(wB.z), u2h(wB.w), u2h(wC.x) };
    const __half2 b2 = u2h(dwb2[p*64 + lane]);
    __half2 acc[8];
    #pragma unroll
    for (int px = 0; px < 8; ++px) acc[px] = b2;
    #pragma unroll
    for (int dy = 0; dy < 3; ++dy)
      #pragma unroll
      for (int dx = 0; dx < 3; ++dx){
        const __half2 w2 = w9[dy*3+dx];
        #pragma unroll
        for (int px = 0; px < 8; ++px)
          acc[px] = __hfma2(hx[dy][px+dx], w2, acc[px]);
      }
    #pragma unroll
    for (int px = 0; px < 8; ++px)
      *reinterpret_cast<unsigned int*>(tmpb + swz256(y*8+px, 4*lane)) = relu2u(acc[px]);
  };

  // ================= K pipeline =================
  dw_pass(1);            // X_k -> tmpb
  __syncthreads();       // (a) X_k visible; W_k staged
  {
    #pragma unroll
    for (int nh = 0; nh < 2; ++nh){
      f32x4 a2[2] = {{0.f,0.f,0.f,0.f},{0.f,0.f,0.f,0.f}};
      #pragma unroll
      for (int ks = 0; ks < 4; ++ks){
        const f16x8 af = *reinterpret_cast<const f16x8*>(tmpb + swz256(mt*16+c16, ks*64 + g*16));
        #pragma unroll
        for (int j = 0; j < 2; ++j){
          const f16x8 bf = *reinterpret_cast<const f16x8*>(wl + (((ntb+nh*2+j)*4 + ks)*64 + lane)*16);
          a2[j] = __builtin_amdgcn_mfma_f32_16x16x32_f16(af, bf, a2[j], 0, 0, 0);
        }
      }
      #pragma unroll
      for (int j = 0; j < 2; ++j){
        const int co = (ntb+nh*2+j)*16 + c16;
        const float bias = kpwb[co];
        const unsigned int u01 = pkh(a2[j][0]+bias, a2[j][1]+bias);
        const unsigned int u23 = pkh(a2[j][2]+bias, a2[j][3]+bias);
        *reinterpret_cast<ushort*>(kb + swz256(n0+0, 2*co)) = (ushort)u01;
        *reinterpret_cast<ushort*>(kb + swz256(n0+1, 2*co)) = (ushort)(u01 >> 16);
        *reinterpret_cast<ushort*>(kb + swz256(n0+2, 2*co)) = (ushort)u23;
        *reinterpret_cast<ushort*>(kb + swz256(n0+3, 2*co)) = (ushort)(u23 >> 16);
      }
    }
  }
  __syncthreads();       // (b) tmpb + wl reads done; K visible

  // ================= V pipeline =================
  stage_w(2);            // W_v flies under conv_v
  dw_pass(2);            // X_v -> tmpb
  __syncthreads();       // (c) X_v visible; W_v staged
  {
    #pragma unroll
    for (int nh = 0; nh < 2; ++nh){
      f32x4 a2[2] = {{0.f,0.f,0.f,0.f},{0.f,0.f,0.f,0.f}};
      #pragma unroll
      for (int ks = 0; ks < 4; ++ks){
        const f16x8 af = *reinterpret_cast<const f16x8*>(tmpb + swz256(mt*16+c16, ks*64 + g*16));
        #pragma unroll
        for (int j = 0; j < 2; ++j){
          const f16x8 bf = *reinterpret_cast<const f16x8*>(wl + (((ntb+nh*2+j)*4 + ks)*64 + lane)*16);
          a2[j] = __builtin_amdgcn_mfma_f32_16x16x32_f16(af, bf, a2[j], 0, 0, 0);
        }
      }
      #pragma unroll
      for (int j = 0; j < 2; ++j){      // V^T direct to vb (region untouched elsewhere)
        const int co = (ntb+nh*2+j)*16 + c16;
        const float bias = vpwb[co];
        const uint2 pk2 = make_uint2(pkh(a2[j][0]+bias, a2[j][1]+bias),
                                     pkh(a2[j][2]+bias, a2[j][3]+bias));
        *reinterpret_cast<uint2*>(vb + swz128(co, 2*n0)) = pk2;
      }
    }
  }
  __syncthreads();       // (d) tmpb + wl reads done; V^T visible

  // ================= Q pipeline (hx dies in conv_q) =================
  stage_w(0);            // W_q flies under conv_q
  dw_pass(0);            // X_q -> tmpb   (last use of hx)
  __syncthreads();       // (e) X_q visible; W_q staged
  f16x8 qfrag[2];
  {
    uint2 pkq[2][2];
    #pragma unroll
    for (int dt = 0; dt < 2; ++dt){
      f32x4 aq[2] = {{0.f,0.f,0.f,0.f},{0.f,0.f,0.f,0.f}};
      #pragma unroll
      for (int ks = 0; ks < 4; ++ks){
        const f16x8 awf = *reinterpret_cast<const f16x8*>(wl + (((he*2+dt)*4 + ks)*64 + lane)*16);
        #pragma unroll
        for (int qt = 0; qt < 2; ++qt){
          const f16x8 btf = *reinterpret_cast<const f16x8*>(tmpb + swz256(half*32+qt*16+c16, ks*64 + g*16));
          aq[qt] = __builtin_amdgcn_mfma_f32_16x16x32_f16(awf, btf, aq[qt], 0, 0, 0);
        }
      }
      const float4 qb4 = *reinterpret_cast<const float4*>(&qpwb[he*32 + dt*16 + g*4]);
      #pragma unroll
      for (int qt = 0; qt < 2; ++qt){
        pkq[dt][qt] = make_uint2(pkh((aq[qt][0]+qb4.x)*SCALE_, (aq[qt][1]+qb4.y)*SCALE_),
                                 pkh((aq[qt][2]+qb4.z)*SCALE_, (aq[qt][3]+qb4.w)*SCALE_));
      }
    }
    #pragma unroll
    for (int qt = 0; qt < 2; ++qt)
      qfrag[qt] = xpose_frag(pkq[0][qt], pkq[1][qt], l0b, l1b, hi);
  }
  __syncthreads();       // (f) tmpb X_q reads + wl W_q reads done

  // ================= attention (QK^T swapped + softmax + PV), O -> tmpb =================
  stage_w(3);            // W_proj flies under attention
  f16x8 pf[2][2];
  #pragma unroll
  for (int qt = 0; qt < 2; ++qt){
    f32x4 st[4];
    #pragma unroll
    for (int m2 = 0; m2 < 4; ++m2){
      const f16x8 kf = *reinterpret_cast<const f16x8*>(kb + swz256(m2*16 + c16, he*64 + g*16));
      const f32x4 z = {0.f,0.f,0.f,0.f};
      st[m2] = __builtin_amdgcn_mfma_f32_16x16x32_f16(kf, qfrag[qt], z, 0, 0, 0);
    }
    const int n = half*32 + qt*16 + c16;
    float mx = -1e30f;
    #pragma unroll
    for (int m2 = 0; m2 < 4; ++m2){
      const float4 bx = *reinterpret_cast<const float4*>(&biasx[(((he*4+m2)*64 + n) << 4) + (g << 2)]);
      st[m2][0] += bx.x; st[m2][1] += bx.y; st[m2][2] += bx.z; st[m2][3] += bx.w;
      mx = fmaxf(mx, fmaxf(fmaxf(st[m2][0], st[m2][1]), fmaxf(st[m2][2], st[m2][3])));
    }
    mx = fmaxf(mx, __shfl_xor(mx, 16));
    mx = fmaxf(mx, __shfl_xor(mx, 32));
    float ls = 0.f;
    #pragma unroll
    for (int m2 = 0; m2 < 4; ++m2){
      #pragma unroll
      for (int r = 0; r < 4; ++r){
        st[m2][r] = __expf(st[m2][r] - mx);
        ls += st[m2][r];
      }
    }
    ls += __shfl_xor(ls, 16);
    ls += __shfl_xor(ls, 32);
    const float inv = 1.0f / ls;
    uint2 pk[4];
    #pragma unroll
    for (int m2 = 0; m2 < 4; ++m2)
      pk[m2] = make_uint2(pkh(st[m2][0]*inv, st[m2][1]*inv),
                          pkh(st[m2][2]*inv, st[m2][3]*inv));
    #pragma unroll
    for (int ks = 0; ks < 2; ++ks)
      pf[qt][ks] = xpose_frag(pk[2*ks], pk[2*ks+1], l0b, l1b, hi);
  }
  // PV: A=pf regs, B=V^T in vb; O -> tmpb (X_q reads finished at (f))
  {
    f32x4 o[2][2];
    #pragma unroll
    for (int qt = 0; qt < 2; ++qt)
      #pragma unroll
      for (int dt = 0; dt < 2; ++dt) o[qt][dt] = (f32x4){0.f,0.f,0.f,0.f};
    #pragma unroll
    for (int ks = 0; ks < 2; ++ks){
      #pragma unroll
      for (int dt = 0; dt < 2; ++dt){
        const f16x8 vf = *reinterpret_cast<const f16x8*>(vb + swz128(he*32+dt*16+c16, ks*64 + g*16));
        #pragma unroll
        for (int qt = 0; qt < 2; ++qt)
          o[qt][dt] = __builtin_amdgcn_mfma_f32_16x16x32_f16(pf[qt][ks], vf, o[qt][dt], 0, 0, 0);
      }
    }
    #pragma unroll
    for (int qt = 0; qt < 2; ++qt)
      #pragma unroll
      for (int dt = 0; dt < 2; ++dt){
        const int d2 = he*32 + dt*16 + c16;
        const int nb = half*32 + qt*16 + g*4;
        const unsigned int u01 = pkh(o[qt][dt][0], o[qt][dt][1]);
        const unsigned int u23 = pkh(o[qt][dt][2], o[qt][dt][3]);
        *reinterpret_cast<ushort*>(tmpb + swz256(nb+0, 2*d2)) = (ushort)u01;
        *reinterpret_cast<ushort*>(tmpb + swz256(nb+1, 2*d2)) = (ushort)(u01 >> 16);
        *reinterpret_cast<ushort*>(tmpb + swz256(nb+2, 2*d2)) = (ushort)u23;
        *reinterpret_cast<ushort*>(tmpb + swz256(nb+3, 2*d2)) = (ushort)(u23 >> 16);
      }
  }
  __syncthreads();       // (g) O visible; W_proj staged

  // ================= projection GEMM + output =================
  {
    #pragma unroll
    for (int nh = 0; nh < 2; ++nh){
      f32x4 a2[2] = {{0.f,0.f,0.f,0.f},{0.f,0.f,0.f,0.f}};
      #pragma unroll
      for (int ks = 0; ks < 4; ++ks){
        const f16x8 af = *reinterpret_cast<const f16x8*>(tmpb + swz256(mt*16+c16, ks*64 + g*16));
        #pragma unroll
        for (int j = 0; j < 2; ++j){
          const f16x8 bf = *reinterpret_cast<const f16x8*>(wl + (((ntb+nh*2+j)*4 + ks)*64 + lane)*16);
          a2[j] = __builtin_amdgcn_mfma_f32_16x16x32_f16(af, bf, a2[j], 0, 0, 0);
        }
      }
      #pragma unroll
      for (int j = 0; j < 2; ++j){
        const int co = (ntb+nh*2+j)*16 + c16;
        const float bias = pjb[co];
        #pragma unroll
        for (int r = 0; r < 4; ++r){
          const int n = n0 + r;
          out[(((long)t*H_ + (h0+(n>>3)))*W_ + (w0+(n&7)))*C_ + co] = a2[j][r] + bias;
        }
      }
    }
  }
}

extern "C" void kernel_launch(void* const* d_in, const int* in_sizes, int n_in,
                              void* d_out, int out_size, void* d_ws, size_t ws_size,
                              hipStream_t stream) {
  const float* vid  = (const float*)d_in[0];
  const float* rpb  = (const float*)d_in[1];
  const float* qdw  = (const float*)d_in[2];
  const float* qdwb = (const float*)d_in[3];
  const float* qpw  = (const float*)d_in[4];
  const float* qpwb = (const float*)d_in[5];
  const float* kdw  = (const float*)d_in[6];
  const float* kdwb = (const float*)d_in[7];
  const float* kpw  = (const float*)d_in[8];
  const float* kpwb = (const float*)d_in[9];
  const float* vdw  = (const float*)d_in[10];
  const float* vdwb = (const float*)d_in[11];
  const float* vpw  = (const float*)d_in[12];
  const float* vpwb = (const float*)d_in[13];
  const float* pjw  = (const float*)d_in[14];
  const float* pjb  = (const float*)d_in[15];
  float* outp = (float*)d_out;

  ushort*       wfrag = (ushort*)((char*)d_ws + WS_WFRAG);
  float*        biasx = (float*)((char*)d_ws + WS_BIASX);
  unsigned int* dwf   = (unsigned int*)((char*)d_ws + WS_DWF);
  unsigned int* dwb2  = (unsigned int*)((char*)d_ws + WS_DWB);

  prep_kernel<<<dim3(106), dim3(256), 0, stream>>>(
      qpw, kpw, vpw, pjw, rpb, qdw, kdw, vdw, qdwb, kdwb, vdwb,
      wfrag, biasx, dwf, dwb2);
  winattn_v4<<<dim3(NWIN_), dim3(512), 0, stream>>>(
      vid, qpwb, kpwb, vpwb, pjb, wfrag, biasx, dwf, dwb2, outp);
}

// Round 15
// 162.500 us; speedup vs baseline: 2.3014x; 1.0134x over previous
//
#include <hip/hip_runtime.h>
#include <hip/hip_fp16.h>
#include <stdint.h>

#define T_ 2
#define H_ 384
#define W_ 384
#define C_ 128
#define HN_ 48
#define WN_ 48
#define NWIN_ (T_*HN_*WN_)
#define SCALE_ 0.17677669529663687f

typedef float f32x4 __attribute__((ext_vector_type(4)));
typedef _Float16 f16x8 __attribute__((ext_vector_type(8)));

// ---- workspace ----
#define WS_WFRAG 0        // 4 mats x [nt8][ks][lane][8] f16 = 131072 B (fragment-linear)
#define WS_BIASX 131072   // [he][m2][n][gr] f32 = 65536 B (S^T-fragment layout)
#define WS_DWF   196608   // [3][64 cp][12] half2-as-uint = 9216 B
#define WS_DWB   205824   // [3][64 cp] half2-as-uint = 768 B

// ---- LDS: 80 KB ----
// tmp: X_k -> V^T[128][128B] | kb: X_q -> K | vb: X_v -> O | wl: staged W (32KB)
#define TMP_OFF 0
#define KB_OFF  16384
#define VB_OFF  32768
#define WL_OFF  49152
#define SMEM_SZ 81920

#define GLOBAL_AS __attribute__((address_space(1)))
#define LDS_AS    __attribute__((address_space(3)))

__device__ __forceinline__ void g2l16(const void* g, void* l){
  __builtin_amdgcn_global_load_lds((const GLOBAL_AS unsigned int*)g,
                                   (LDS_AS unsigned int*)l, 16, 0, 0);
}

__device__ __forceinline__ unsigned int pkh(float a, float b){
  union{__half2 h; unsigned int u;} c;
  c.h = __float22half2_rn(make_float2(a, b));
  return c.u;
}
__device__ __forceinline__ unsigned short f2h(float f){
  union{__half h; unsigned short u;} c; c.h = __float2half_rn(f); return c.u;
}
__device__ __forceinline__ __half2 u2h(unsigned int u){
  union{unsigned int u; __half2 h;} c; c.u = u; return c.h;
}
// packed-half ReLU via sign-mask (exact for non-NaN)
__device__ __forceinline__ unsigned int relu2u(__half2 v){
  union{__half2 h; unsigned int u;} c; c.h = v;
  const unsigned int m = ((c.u >> 15) & 0x00010001u) * 0xFFFFu;
  return c.u & ~m;
}
__device__ __forceinline__ int swz256(int row, int b){ return row*256 + (b ^ ((row & 15) << 4)); }
__device__ __forceinline__ int swz128(int row, int b){ return row*128 + (b ^ ((row & 7) << 4)); }

// C-frag(col=c16,row=g*4+r, 2 tiles) -> A/B-frag(row=c16,k=g*8+e)  [proven r7/r11/r14]
__device__ __forceinline__ f16x8 xpose_frag(uint2 a, uint2 b, int l0b, int l1b, int hi){
  union{ f16x8 v; unsigned int u[4]; } r;
  const unsigned x0 = __builtin_amdgcn_ds_bpermute(l0b, (int)a.x);
  const unsigned y0 = __builtin_amdgcn_ds_bpermute(l0b, (int)b.x);
  const unsigned x1 = __builtin_amdgcn_ds_bpermute(l0b, (int)a.y);
  const unsigned y1 = __builtin_amdgcn_ds_bpermute(l0b, (int)b.y);
  const unsigned x2 = __builtin_amdgcn_ds_bpermute(l1b, (int)a.x);
  const unsigned y2 = __builtin_amdgcn_ds_bpermute(l1b, (int)b.x);
  const unsigned x3 = __builtin_amdgcn_ds_bpermute(l1b, (int)a.y);
  const unsigned y3 = __builtin_amdgcn_ds_bpermute(l1b, (int)b.y);
  r.u[0] = hi ? y0 : x0; r.u[1] = hi ? y1 : x1;
  r.u[2] = hi ? y2 : x2; r.u[3] = hi ? y3 : x3;
  return r.v;
}

// ---------- prep: weights -> f16 fragment-linear; rpb -> S^T-layout bias; dw packed ----------
__global__ __launch_bounds__(256)
void prep_kernel(const float* __restrict__ qpw, const float* __restrict__ kpw,
                 const float* __restrict__ vpw, const float* __restrict__ pjw,
                 const float* __restrict__ rpb,
                 const float* __restrict__ qdw, const float* __restrict__ kdw,
                 const float* __restrict__ vdw,
                 const float* __restrict__ qdwb, const float* __restrict__ kdwb,
                 const float* __restrict__ vdwb,
                 ushort* __restrict__ wfrag, float* __restrict__ biasx,
                 unsigned int* __restrict__ dwf, unsigned int* __restrict__ dwb2)
{
  const int idx = blockIdx.x*256 + threadIdx.x;
  if (idx < 8192) {
    const int mat = idx >> 11, rem = idx & 2047;
    const int nt8 = rem >> 8, ks = (rem >> 6) & 3, lane = rem & 63;
    const int c16 = lane & 15, g = lane >> 4;
    const float* Ws[4] = {qpw, kpw, vpw, pjw};
    const float* src = Ws[mat] + (nt8*16 + c16)*128 + ks*32 + g*8;
    ushort* dst = wfrag + idx*8;
    #pragma unroll
    for (int e = 0; e < 8; ++e) dst[e] = f2h(src[e]);
  } else if (idx < 24576) {
    // bias in S^T fragment layout: i2 = ((he*4+m2)*64+n)*16 + g*4 + r
    const int i2 = idx - 8192;
    const int he = i2 >> 12;
    const int m2 = (i2 >> 10) & 3;
    const int n  = (i2 >> 4) & 63;
    const int gr = i2 & 15;
    const int m  = m2*16 + gr;
    const int ny = n >> 3, nx = n & 7, my = m >> 3, mx = m & 7;
    biasx[i2] = rpb[((ny - my + 7)*15 + (nx - mx + 7))*4 + he];
  } else if (idx < 24576 + 2304) {
    const int i2 = idx - 24576;
    const int p = i2 / 768, rem = i2 % 768, cp = rem / 12, j = rem % 12;
    const float* dws[3] = {qdw, kdw, vdw};
    unsigned int v = 0;
    if (j < 9) v = pkh(dws[p][(2*cp)*9 + j], dws[p][(2*cp+1)*9 + j]);
    dwf[(p*64 + cp)*12 + j] = v;
  } else if (idx < 24576 + 2304 + 192) {
    const int i2 = idx - 24576 - 2304;
    const int p = i2 >> 6, cp = i2 & 63;
    const float* dbs[3] = {qdwb, kdwb, vdwb};
    dwb2[p*64 + cp] = pkh(dbs[p][2*cp], dbs[p][2*cp+1]);
  }
}

// ---------- main: 7 phases / 6 barriers; convs consolidated; Q-weights from L2 ----------
__global__ __launch_bounds__(512, 8)
void winattn_v5(const float* __restrict__ vid,
                const float* __restrict__ qpwb, const float* __restrict__ kpwb,
                const float* __restrict__ vpwb, const float* __restrict__ pjb,
                const ushort* __restrict__ wfrag, const float* __restrict__ biasx,
                const unsigned int* __restrict__ dwf, const unsigned int* __restrict__ dwb2,
                float* __restrict__ out)
{
  __shared__ __attribute__((aligned(16))) char smem[SMEM_SZ];
  char* tmpb = smem + TMP_OFF;   // X_k -> V^T
  char* kb   = smem + KB_OFF;    // X_q -> K
  char* vb   = smem + VB_OFF;    // X_v -> O
  char* wl   = smem + WL_OFF;    // staged weight matrix (32KB, fragment-linear)

  const int tid  = threadIdx.x;
  const int w    = tid >> 6;
  const int lane = tid & 63;
  const int g    = lane >> 4;
  const int c16  = lane & 15;
  const int hi   = (lane >= 32);
  const int l0b  = (((g & 1) << 5) + c16) << 2;
  const int l1b  = l0b + 64;

  // async-stage one 32KB weight matrix into wl (no VGPR cost)
  auto stage_w = [&](int m){
    const char* gsrc = reinterpret_cast<const char*>(wfrag) + m*32768;
    #pragma unroll
    for (int i2 = 0; i2 < 4; ++i2){
      const int off = (i2*512 + tid)*16;
      g2l16(gsrc + off, wl + off);
    }
  };

  // XCD-aware bijective swizzle (4608 % 8 == 0)
  const int wid = (blockIdx.x & 7) * (NWIN_ / 8) + (blockIdx.x >> 3);
  const int t  = wid / (HN_*WN_);
  const int hw = wid % (HN_*WN_);
  const int hn = hw / WN_, wn = hw % WN_;
  const int h0 = hn*8, w0 = wn*8;

  const int mt  = w & 3;
  const int ntb = (w >> 2) * 4;
  const int n0  = mt*16 + g*4;
  const int he = w >> 1, half = w & 1;
  const int y = w;

  stage_w(1);   // W_k flies under halo load + all three convs

  // ================= phase 0: halo + conv x3 (hx dies here) =================
  {
    __half2 hx[3][10];
    #pragma unroll
    for (int dy = 0; dy < 3; ++dy){
      const int hh = h0 + y - 1 + dy;
      const bool rv = (unsigned)hh < (unsigned)H_;
      #pragma unroll
      for (int xc = 0; xc < 10; ++xc){
        const int ww = w0 - 1 + xc;
        float2 l = make_float2(0.f, 0.f);
        if (rv && (unsigned)ww < (unsigned)W_)
          l = *reinterpret_cast<const float2*>(&vid[(((long)t*H_ + hh)*W_ + ww)*C_ + 2*lane]);
        hx[dy][xc] = __float22half2_rn(l);
      }
    }
    auto dw_pass = [&](int p, char* dst){
      const uint4* dq = reinterpret_cast<const uint4*>(dwf + (p*64 + lane)*12);
      const uint4 wA = dq[0], wB = dq[1], wC = dq[2];
      const __half2 w9[9] = { u2h(wA.x), u2h(wA.y), u2h(wA.z), u2h(wA.w),
                              u2h(wB.x), u2h(wB.y), u2h(wB.z), u2h(wB.w), u2h(wC.x) };
      const __half2 b2 = u2h(dwb2[p*64 + lane]);
      __half2 acc[8];
      #pragma unroll
      for (int px = 0; px < 8; ++px) acc[px] = b2;
      #pragma unroll
      for (int dy = 0; dy < 3; ++dy)
        #pragma unroll
        for (int dx = 0; dx < 3; ++dx){
          const __half2 w2 = w9[dy*3+dx];
          #pragma unroll
          for (int px = 0; px < 8; ++px)
            acc[px] = __hfma2(hx[dy][px+dx], w2, acc[px]);
        }
      #pragma unroll
      for (int px = 0; px < 8; ++px)
        *reinterpret_cast<unsigned int*>(dst + swz256(y*8+px, 4*lane)) = relu2u(acc[px]);
    };
    dw_pass(1, tmpb);   // X_k
    dw_pass(2, vb);     // X_v
    dw_pass(0, kb);     // X_q  (last use of hx)
  }
  __syncthreads();       // (a) X_k, X_v, X_q visible; W_k staged+drained

  // ================= phase 1: Q-GEMM (swapped; A=Wq frags from L2, B=X_q in kb) ========
  f16x8 qfrag[2];
  {
    uint2 pkq[2][2];
    #pragma unroll
    for (int dt = 0; dt < 2; ++dt){
      f32x4 aq[2] = {{0.f,0.f,0.f,0.f},{0.f,0.f,0.f,0.f}};
      #pragma unroll
      for (int ks = 0; ks < 4; ++ks){
        const f16x8 awf = *reinterpret_cast<const f16x8*>(&wfrag[(((he*2+dt)*4 + ks)*64 + lane)*8]);
        #pragma unroll
        for (int qt = 0; qt < 2; ++qt){
          const f16x8 btf = *reinterpret_cast<const f16x8*>(kb + swz256(half*32+qt*16+c16, ks*64 + g*16));
          aq[qt] = __builtin_amdgcn_mfma_f32_16x16x32_f16(awf, btf, aq[qt], 0, 0, 0);
        }
      }
      const float4 qb4 = *reinterpret_cast<const float4*>(&qpwb[he*32 + dt*16 + g*4]);
      #pragma unroll
      for (int qt = 0; qt < 2; ++qt){
        pkq[dt][qt] = make_uint2(pkh((aq[qt][0]+qb4.x)*SCALE_, (aq[qt][1]+qb4.y)*SCALE_),
                                 pkh((aq[qt][2]+qb4.z)*SCALE_, (aq[qt][3]+qb4.w)*SCALE_));
      }
    }
    #pragma unroll
    for (int qt = 0; qt < 2; ++qt)
      qfrag[qt] = xpose_frag(pkq[0][qt], pkq[1][qt], l0b, l1b, hi);
  }
  __syncthreads();       // (b) X_q reads done -> kb reusable

  // ================= phase 2: K-GEMM (A=X_k in tmpb, B=Wk in wl) -> K into kb =========
  {
    #pragma unroll
    for (int nh = 0; nh < 2; ++nh){
      f32x4 a2[2] = {{0.f,0.f,0.f,0.f},{0.f,0.f,0.f,0.f}};
      #pragma unroll
      for (int ks = 0; ks < 4; ++ks){
        const f16x8 af = *reinterpret_cast<const f16x8*>(tmpb + swz256(mt*16+c16, ks*64 + g*16));
        #pragma unroll
        for (int j = 0; j < 2; ++j){
          const f16x8 bf = *reinterpret_cast<const f16x8*>(wl + (((ntb+nh*2+j)*4 + ks)*64 + lane)*16);
          a2[j] = __builtin_amdgcn_mfma_f32_16x16x32_f16(af, bf, a2[j], 0, 0, 0);
        }
      }
      #pragma unroll
      for (int j = 0; j < 2; ++j){
        const int co = (ntb+nh*2+j)*16 + c16;
        const float bias = kpwb[co];
        const unsigned int u01 = pkh(a2[j][0]+bias, a2[j][1]+bias);
        const unsigned int u23 = pkh(a2[j][2]+bias, a2[j][3]+bias);
        *reinterpret_cast<ushort*>(kb + swz256(n0+0, 2*co)) = (ushort)u01;
        *reinterpret_cast<ushort*>(kb + swz256(n0+1, 2*co)) = (ushort)(u01 >> 16);
        *reinterpret_cast<ushort*>(kb + swz256(n0+2, 2*co)) = (ushort)u23;
        *reinterpret_cast<ushort*>(kb + swz256(n0+3, 2*co)) = (ushort)(u23 >> 16);
      }
    }
  }
  __syncthreads();       // (c) K visible; tmpb X_k reads + wl Wk reads done

  // ================= phase 3: stage Wv; QK^T (swapped) + softmax -> pf regs ===========
  stage_w(2);            // W_v flies under QK^T+softmax
  f16x8 pf[2][2];
  #pragma unroll
  for (int qt = 0; qt < 2; ++qt){
    f32x4 st[4];
    #pragma unroll
    for (int m2 = 0; m2 < 4; ++m2){
      const f16x8 kf = *reinterpret_cast<const f16x8*>(kb + swz256(m2*16 + c16, he*64 + g*16));
      const f32x4 z = {0.f,0.f,0.f,0.f};
      st[m2] = __builtin_amdgcn_mfma_f32_16x16x32_f16(kf, qfrag[qt], z, 0, 0, 0);
    }
    const int n = half*32 + qt*16 + c16;
    float mx = -1e30f;
    #pragma unroll
    for (int m2 = 0; m2 < 4; ++m2){
      const float4 bx = *reinterpret_cast<const float4*>(&biasx[(((he*4+m2)*64 + n) << 4) + (g << 2)]);
      st[m2][0] += bx.x; st[m2][1] += bx.y; st[m2][2] += bx.z; st[m2][3] += bx.w;
      mx = fmaxf(mx, fmaxf(fmaxf(st[m2][0], st[m2][1]), fmaxf(st[m2][2], st[m2][3])));
    }
    mx = fmaxf(mx, __shfl_xor(mx, 16));
    mx = fmaxf(mx, __shfl_xor(mx, 32));
    float ls = 0.f;
    #pragma unroll
    for (int m2 = 0; m2 < 4; ++m2){
      #pragma unroll
      for (int r = 0; r < 4; ++r){
        st[m2][r] = __expf(st[m2][r] - mx);
        ls += st[m2][r];
      }
    }
    ls += __shfl_xor(ls, 16);
    ls += __shfl_xor(ls, 32);
    const float inv = 1.0f / ls;
    uint2 pk[4];
    #pragma unroll
    for (int m2 = 0; m2 < 4; ++m2)
      pk[m2] = make_uint2(pkh(st[m2][0]*inv, st[m2][1]*inv),
                          pkh(st[m2][2]*inv, st[m2][3]*inv));
    #pragma unroll
    for (int ks = 0; ks < 2; ++ks)
      pf[qt][ks] = xpose_frag(pk[2*ks], pk[2*ks+1], l0b, l1b, hi);
  }
  __syncthreads();       // (d) kb K reads done; Wv staged+drained

  // ================= phase 4: V-GEMM (A=X_v in vb, B=Wv in wl) -> V^T into tmpb =======
  {
    #pragma unroll
    for (int nh = 0; nh < 2; ++nh){
      f32x4 a2[2] = {{0.f,0.f,0.f,0.f},{0.f,0.f,0.f,0.f}};
      #pragma unroll
      for (int ks = 0; ks < 4; ++ks){
        const f16x8 af = *reinterpret_cast<const f16x8*>(vb + swz256(mt*16+c16, ks*64 + g*16));
        #pragma unroll
        for (int j = 0; j < 2; ++j){
          const f16x8 bf = *reinterpret_cast<const f16x8*>(wl + (((ntb+nh*2+j)*4 + ks)*64 + lane)*16);
          a2[j] = __builtin_amdgcn_mfma_f32_16x16x32_f16(af, bf, a2[j], 0, 0, 0);
        }
      }
      #pragma unroll
      for (int j = 0; j < 2; ++j){      // V^T direct into tmpb (X_k dead since (c))
        const int co = (ntb+nh*2+j)*16 + c16;
        const float bias = vpwb[co];
        const uint2 pk2 = make_uint2(pkh(a2[j][0]+bias, a2[j][1]+bias),
                                     pkh(a2[j][2]+bias, a2[j][3]+bias));
        *reinterpret_cast<uint2*>(tmpb + swz128(co, 2*n0)) = pk2;
      }
    }
  }
  __syncthreads();       // (e) V^T visible; vb X_v reads + wl Wv reads done

  // ================= phase 5: stage Wproj; PV (A=pf regs, B=V^T) -> O into vb =========
  stage_w(3);            // W_proj flies under PV
  {
    f32x4 o[2][2];
    #pragma unroll
    for (int qt = 0; qt < 2; ++qt)
      #pragma unroll
      for (int dt = 0; dt < 2; ++dt) o[qt][dt] = (f32x4){0.f,0.f,0.f,0.f};
    #pragma unroll
    for (int ks = 0; ks < 2; ++ks){
      #pragma unroll
      for (int dt = 0; dt < 2; ++dt){
        const f16x8 vf = *reinterpret_cast<const f16x8*>(tmpb + swz128(he*32+dt*16+c16, ks*64 + g*16));
        #pragma unroll
        for (int qt = 0; qt < 2; ++qt)
          o[qt][dt] = __builtin_amdgcn_mfma_f32_16x16x32_f16(pf[qt][ks], vf, o[qt][dt], 0, 0, 0);
      }
    }
    #pragma unroll
    for (int qt = 0; qt < 2; ++qt)
      #pragma unroll
      for (int dt = 0; dt < 2; ++dt){
        const int d2 = he*32 + dt*16 + c16;
        const int nb = half*32 + qt*16 + g*4;
        const unsigned int u01 = pkh(o[qt][dt][0], o[qt][dt][1]);
        const unsigned int u23 = pkh(o[qt][dt][2], o[qt][dt][3]);
        *reinterpret_cast<ushort*>(vb + swz256(nb+0, 2*d2)) = (ushort)u01;
        *reinterpret_cast<ushort*>(vb + swz256(nb+1, 2*d2)) = (ushort)(u01 >> 16);
        *reinterpret_cast<ushort*>(vb + swz256(nb+2, 2*d2)) = (ushort)u23;
        *reinterpret_cast<ushort*>(vb + swz256(nb+3, 2*d2)) = (ushort)(u23 >> 16);
      }
  }
  __syncthreads();       // (f) O visible; Wproj staged+drained

  // ================= phase 6: projection GEMM + output =================
  {
    #pragma unroll
    for (int nh = 0; nh < 2; ++nh){
      f32x4 a2[2] = {{0.f,0.f,0.f,0.f},{0.f,0.f,0.f,0.f}};
      #pragma unroll
      for (int ks = 0; ks < 4; ++ks){
        const f16x8 af = *reinterpret_cast<const f16x8*>(vb + swz256(mt*16+c16, ks*64 + g*16));
        #pragma unroll
        for (int j = 0; j < 2; ++j){
          const f16x8 bf = *reinterpret_cast<const f16x8*>(wl + (((ntb+nh*2+j)*4 + ks)*64 + lane)*16);
          a2[j] = __builtin_amdgcn_mfma_f32_16x16x32_f16(af, bf, a2[j], 0, 0, 0);
        }
      }
      #pragma unroll
      for (int j = 0; j < 2; ++j){
        const int co = (ntb+nh*2+j)*16 + c16;
        const float bias = pjb[co];
        #pragma unroll
        for (int r = 0; r < 4; ++r){
          const int n = n0 + r;
          out[(((long)t*H_ + (h0+(n>>3)))*W_ + (w0+(n&7)))*C_ + co] = a2[j][r] + bias;
        }
      }
    }
  }
}

extern "C" void kernel_launch(void* const* d_in, const int* in_sizes, int n_in,
                              void* d_out, int out_size, void* d_ws, size_t ws_size,
                              hipStream_t stream) {
  const float* vid  = (const float*)d_in[0];
  const float* rpb  = (const float*)d_in[1];
  const float* qdw  = (const float*)d_in[2];
  const float* qdwb = (const float*)d_in[3];
  const float* qpw  = (const float*)d_in[4];
  const float* qpwb = (const float*)d_in[5];
  const float* kdw  = (const float*)d_in[6];
  const float* kdwb = (const float*)d_in[7];
  const float* kpw  = (const float*)d_in[8];
  const float* kpwb = (const float*)d_in[9];
  const float* vdw  = (const float*)d_in[10];
  const float* vdwb = (const float*)d_in[11];
  const float* vpw  = (const float*)d_in[12];
  const float* vpwb = (const float*)d_in[13];
  const float* pjw  = (const float*)d_in[14];
  const float* pjb  = (const float*)d_in[15];
  float* outp = (float*)d_out;

  ushort*       wfrag = (ushort*)((char*)d_ws + WS_WFRAG);
  float*        biasx = (float*)((char*)d_ws + WS_BIASX);
  unsigned int* dwf   = (unsigned int*)((char*)d_ws + WS_DWF);
  unsigned int* dwb2  = (unsigned int*)((char*)d_ws + WS_DWB);

  prep_kernel<<<dim3(106), dim3(256), 0, stream>>>(
      qpw, kpw, vpw, pjw, rpb, qdw, kdw, vdw, qdwb, kdwb, vdwb,
      wfrag, biasx, dwf, dwb2);
  winattn_v5<<<dim3(NWIN_), dim3(512), 0, stream>>>(
      vid, qpwb, kpwb, vpwb, pjb, wfrag, biasx, dwf, dwb2, outp);
}